// Round 1
// baseline (15.577 us; speedup 1.0000x reference)
//
#include <hip/hip_runtime.h>

// Reference collapses analytically:
//   softmax over axis=-2 (n) => column sums are exactly 1
//   colsum[b,i,m] = sum_n sum_{j!=i} sm[b,i,j,n,m] = F-1 = 31  (constant)
//   out[b,i,d]    = 31 * sum_n tgt[b,i,n,d]
//
// Shapes: tgt [B=16, F=32, N=64, D=512] fp32 -> out [16, 32, 512] fp32.
// Pure memory-bound reduction: 67 MB read, 1 MB write.

__global__ __launch_bounds__(256) void rffr_colsum_kernel(
    const float4* __restrict__ tgt, float4* __restrict__ out) {
    // One block per (b,f) row. D = 512 floats = 128 float4 columns.
    const int bf  = blockIdx.x;       // 0..511
    const int tid = threadIdx.x;      // 0..255
    const int col = tid & 127;        // float4 column
    const int g   = tid >> 7;         // n-group: 0 -> n in [0,32), 1 -> [32,64)

    const float4* base = tgt + (size_t)bf * 64 * 128 + (size_t)g * 32 * 128 + col;

    float4 acc = make_float4(0.f, 0.f, 0.f, 0.f);
#pragma unroll
    for (int n = 0; n < 32; ++n) {
        float4 v = base[(size_t)n * 128];
        acc.x += v.x; acc.y += v.y; acc.z += v.z; acc.w += v.w;
    }

    __shared__ float4 part[128];
    if (g == 1) part[col] = acc;
    __syncthreads();
    if (g == 0) {
        float4 p = part[col];
        float4 r;
        r.x = 31.0f * (acc.x + p.x);
        r.y = 31.0f * (acc.y + p.y);
        r.z = 31.0f * (acc.z + p.z);
        r.w = 31.0f * (acc.w + p.w);
        out[(size_t)bf * 128 + col] = r;
    }
}

extern "C" void kernel_launch(void* const* d_in, const int* in_sizes, int n_in,
                              void* d_out, int out_size, void* d_ws, size_t ws_size,
                              hipStream_t stream) {
    const float4* tgt = (const float4*)d_in[0];
    float4* out = (float4*)d_out;
    // B*F = 512 blocks, 256 threads each.
    rffr_colsum_kernel<<<dim3(512), dim3(256), 0, stream>>>(tgt, out);
}

// Round 2
// 15.291 us; speedup vs baseline: 1.0187x; 1.0187x over previous
//
#include <hip/hip_runtime.h>

// Reference collapses analytically:
//   softmax over axis=-2 (n) => column sums are exactly 1
//   colsum[b,i,m] = sum_n sum_{j!=i} sm[b,i,j,n,m] = F-1 = 31  (constant)
//   out[b,i,d]    = 31 * sum_n tgt[b,i,n,d]
//
// Shapes: tgt [B=16, F=32, N=64, D=512] fp32 -> out [16, 32, 512] fp32.
// Pure memory-bound reduction: 67 MB read, 1 MB write.
//
// R1: boost TLP. 2048 blocks (8/CU, 32 waves/CU) instead of 512 (2/CU).
// Each block: one (row, 32-float4-col chunk); each thread sums 8 n values;
// LDS tree-reduce the 8 n-groups.

__global__ __launch_bounds__(256, 8) void rffr_colsum_kernel(
    const float4* __restrict__ tgt, float4* __restrict__ out) {
    const int bid   = blockIdx.x;         // 0..2047
    const int row   = bid >> 2;           // (b*F+f), 0..511
    const int chunk = bid & 3;            // 32-float4 column chunk
    const int tid   = threadIdx.x;        // 0..255
    const int c     = tid & 31;           // col within chunk
    const int g     = tid >> 5;           // n-group 0..7 (8 n each)

    // row stride = 64*128 float4; n stride = 128 float4.
    const float4* base = tgt + (size_t)row * 64 * 128
                             + (size_t)(g * 8) * 128
                             + (size_t)chunk * 32 + c;

    float4 acc = make_float4(0.f, 0.f, 0.f, 0.f);
#pragma unroll
    for (int n = 0; n < 8; ++n) {
        float4 v = base[(size_t)n * 128];
        acc.x += v.x; acc.y += v.y; acc.z += v.z; acc.w += v.w;
    }

    __shared__ float4 part[256];
    part[tid] = acc;
    __syncthreads();
    // Tree reduce over the 8 n-groups (256 -> 128 -> 64 -> 32 lanes).
    if (tid < 128) {
        float4 o = part[tid + 128];
        acc.x += o.x; acc.y += o.y; acc.z += o.z; acc.w += o.w;
        part[tid] = acc;
    }
    __syncthreads();
    if (tid < 64) {
        float4 o = part[tid + 64];
        acc.x += o.x; acc.y += o.y; acc.z += o.z; acc.w += o.w;
        part[tid] = acc;
    }
    __syncthreads();
    if (tid < 32) {
        float4 o = part[tid + 32];
        float4 r;
        r.x = 31.0f * (acc.x + o.x);
        r.y = 31.0f * (acc.y + o.y);
        r.z = 31.0f * (acc.z + o.z);
        r.w = 31.0f * (acc.w + o.w);
        out[(size_t)row * 128 + (size_t)chunk * 32 + c] = r;
    }
}

extern "C" void kernel_launch(void* const* d_in, const int* in_sizes, int n_in,
                              void* d_out, int out_size, void* d_ws, size_t ws_size,
                              hipStream_t stream) {
    const float4* tgt = (const float4*)d_in[0];
    float4* out = (float4*)d_out;
    rffr_colsum_kernel<<<dim3(2048), dim3(256), 0, stream>>>(tgt, out);
}